// Round 1
// baseline (323.248 us; speedup 1.0000x reference)
//
#include <hip/hip_runtime.h>

// ---------------------------------------------------------------------------
// CausalSelfAttention: B=2, T=2048, C=1024, H=16, HD=64
// out = proj( softmax_causal( (xW_attn^T+b) split QKV ) ) with torch Linear.
// Inputs fp32, output fp32; internal compute bf16 MFMA (threshold = 2% max).
// ---------------------------------------------------------------------------

#define B_   2
#define T_   2048
#define C_   1024
#define H_   16
#define HD_  64
#define BT_  (B_ * T_)      // 4096
#define C3_  (3 * C_)       // 3072

typedef __attribute__((ext_vector_type(8))) __bf16 bf16x8;
typedef __attribute__((ext_vector_type(4))) float  f32x4;
typedef __attribute__((ext_vector_type(8))) unsigned short u16x8;

__device__ __forceinline__ unsigned short f2bf(float f) {
    unsigned int u = __float_as_uint(f);
    u = (u + 0x7fffu + ((u >> 16) & 1u)) >> 16;
    return (unsigned short)u;
}

// ---------------- fp32 -> bf16 convert (8 elems/thread) --------------------
__global__ __launch_bounds__(256) void cvt_bf16(const float* __restrict__ in,
                                                unsigned short* __restrict__ out,
                                                int n8) {
    int i = blockIdx.x * 256 + threadIdx.x;
    if (i >= n8) return;
    const float4* p = (const float4*)in;
    float4 f0 = p[i * 2];
    float4 f1 = p[i * 2 + 1];
    u16x8 o;
    o[0] = f2bf(f0.x); o[1] = f2bf(f0.y); o[2] = f2bf(f0.z); o[3] = f2bf(f0.w);
    o[4] = f2bf(f1.x); o[5] = f2bf(f1.y); o[6] = f2bf(f1.z); o[7] = f2bf(f1.w);
    ((u16x8*)out)[i] = o;
}

// ---------------- bf16 GEMM: C[M][N] = A[M][K] * B[N][K]^T + bias ----------
// 128x128 tile, BK=64, 256 threads (4 waves, 2x2), each wave 64x64.
template<int OUT_BF16>
__global__ __launch_bounds__(256) void gemm_bt(const unsigned short* __restrict__ A,
                                               const unsigned short* __restrict__ Bm,
                                               const float* __restrict__ bias,
                                               void* __restrict__ Cv,
                                               int M, int N, int K) {
    __shared__ __align__(16) unsigned short As[128][72];  // +8 pad kills conflicts
    __shared__ __align__(16) unsigned short Bs[128][72];

    const int t    = threadIdx.x;
    const int lane = t & 63;
    const int w    = t >> 6;
    const int wr   = w & 1;
    const int wc   = w >> 1;
    const int l15  = lane & 15;
    const int lhi  = lane >> 4;
    const int m0   = blockIdx.y * 128;
    const int n0   = blockIdx.x * 128;

    f32x4 acc[4][4] = {};

    const int nk = K >> 6;
    for (int kb = 0; kb < nk; ++kb) {
        __syncthreads();
        #pragma unroll
        for (int i = 0; i < 4; ++i) {
            int g   = i * 256 + t;
            int row = g >> 3;
            int kc  = g & 7;
            uint4 va = *(const uint4*)(A  + (size_t)(m0 + row) * K + kb * 64 + kc * 8);
            *(uint4*)(&As[row][kc * 8]) = va;
            uint4 vb = *(const uint4*)(Bm + (size_t)(n0 + row) * K + kb * 64 + kc * 8);
            *(uint4*)(&Bs[row][kc * 8]) = vb;
        }
        __syncthreads();
        #pragma unroll
        for (int kk = 0; kk < 2; ++kk) {
            bf16x8 af[4], bfm[4];
            #pragma unroll
            for (int m = 0; m < 4; ++m)
                af[m] = *(const bf16x8*)(&As[wr * 64 + m * 16 + l15][kk * 32 + lhi * 8]);
            #pragma unroll
            for (int n = 0; n < 4; ++n)
                bfm[n] = *(const bf16x8*)(&Bs[wc * 64 + n * 16 + l15][kk * 32 + lhi * 8]);
            #pragma unroll
            for (int m = 0; m < 4; ++m)
                #pragma unroll
                for (int n = 0; n < 4; ++n)
                    acc[m][n] = __builtin_amdgcn_mfma_f32_16x16x32_bf16(af[m], bfm[n], acc[m][n], 0, 0, 0);
        }
    }

    #pragma unroll
    for (int n = 0; n < 4; ++n) {
        int cg = n0 + wc * 64 + n * 16 + l15;
        float bv = bias[cg];
        #pragma unroll
        for (int m = 0; m < 4; ++m) {
            #pragma unroll
            for (int i = 0; i < 4; ++i) {
                int rg  = m0 + wr * 64 + m * 16 + lhi * 4 + i;
                float v = acc[m][n][i] + bv;
                if (OUT_BF16)
                    ((unsigned short*)Cv)[(size_t)rg * N + cg] = f2bf(v);
                else
                    ((float*)Cv)[(size_t)rg * N + cg] = v;
            }
        }
    }
}

// ---------------- causal flash attention -----------------------------------
// grid = (T/64, B*H); block = 256 (4 waves x 16 q-rows). KV tiles of 64.
__global__ __launch_bounds__(256) void attn_fwd(const unsigned short* __restrict__ qkv,
                                                unsigned short* __restrict__ y) {
    __shared__ __align__(16) unsigned short Ks[64][72];
    __shared__ __align__(16) unsigned short Vt[64][72];   // V transposed: [d][key]
    __shared__ __align__(16) unsigned short Ps[4][16][72];

    const int t    = threadIdx.x;
    const int lane = t & 63;
    const int wv   = t >> 6;
    const int l15  = lane & 15;
    const int lhi  = lane >> 4;
    const int bh   = blockIdx.y;
    const int b    = bh >> 4;
    const int h    = bh & 15;
    const int qt   = gridDim.x - 1 - blockIdx.x;  // biggest tiles first
    const int q0   = qt * 64;
    const size_t rowbase = (size_t)b * T_ * C3_;
    const int hoff = h * HD_;

    // Q fragments live in registers for the whole kernel
    bf16x8 qf[2];
    {
        int qrow = q0 + wv * 16 + l15;
        const unsigned short* qp = qkv + rowbase + (size_t)qrow * C3_ + hoff + lhi * 8;
        qf[0] = *(const bf16x8*)(qp);
        qf[1] = *(const bf16x8*)(qp + 32);
    }

    float Mx[4], Lx[4];
    f32x4 oacc[4];
    #pragma unroll
    for (int i = 0; i < 4; ++i) { Mx[i] = -1e30f; Lx[i] = 0.f; }
    #pragma unroll
    for (int n = 0; n < 4; ++n) oacc[n] = f32x4{0.f, 0.f, 0.f, 0.f};

    const int niter = qt + 1;
    for (int it = 0; it < niter; ++it) {
        const int k0 = it * 64;
        __syncthreads();
        // stage K tile and transposed V tile
        #pragma unroll
        for (int i = 0; i < 2; ++i) {
            int g   = i * 256 + t;
            int row = g >> 3;
            int kc  = g & 7;
            const unsigned short* kp = qkv + rowbase + (size_t)(k0 + row) * C3_ + C_ + hoff + kc * 8;
            *(uint4*)(&Ks[row][kc * 8]) = *(const uint4*)kp;
            const unsigned short* vp = qkv + rowbase + (size_t)(k0 + row) * C3_ + 2 * C_ + hoff + kc * 8;
            union { uint4 u; unsigned short s[8]; } vv;
            vv.u = *(const uint4*)vp;
            #pragma unroll
            for (int j = 0; j < 8; ++j) Vt[kc * 8 + j][row] = vv.s[j];
        }
        __syncthreads();

        // S = Q K^T  (16 q-rows x 64 keys per wave)
        f32x4 sacc[4] = {};
        #pragma unroll
        for (int kk = 0; kk < 2; ++kk) {
            #pragma unroll
            for (int n = 0; n < 4; ++n) {
                bf16x8 kf = *(const bf16x8*)(&Ks[n * 16 + l15][kk * 32 + lhi * 8]);
                sacc[n] = __builtin_amdgcn_mfma_f32_16x16x32_bf16(qf[kk], kf, sacc[n], 0, 0, 0);
            }
        }

        // scale + causal mask
        float p[4][4];
        #pragma unroll
        for (int n = 0; n < 4; ++n) {
            int kg = k0 + n * 16 + l15;
            #pragma unroll
            for (int i = 0; i < 4; ++i) {
                int qg = q0 + wv * 16 + lhi * 4 + i;
                float s = sacc[n][i] * 0.125f;
                p[n][i] = (kg <= qg) ? s : -1e30f;
            }
        }
        // online softmax (row reductions across 16 lanes)
        #pragma unroll
        for (int i = 0; i < 4; ++i) {
            float vmax = fmaxf(fmaxf(p[0][i], p[1][i]), fmaxf(p[2][i], p[3][i]));
            vmax = fmaxf(vmax, __shfl_xor(vmax, 1));
            vmax = fmaxf(vmax, __shfl_xor(vmax, 2));
            vmax = fmaxf(vmax, __shfl_xor(vmax, 4));
            vmax = fmaxf(vmax, __shfl_xor(vmax, 8));
            float Mn    = fmaxf(Mx[i], vmax);
            float alpha = __expf(Mx[i] - Mn);
            Mx[i] = Mn;
            float rs = 0.f;
            #pragma unroll
            for (int n = 0; n < 4; ++n) {
                float e = __expf(p[n][i] - Mn);
                p[n][i] = e;
                rs += e;
            }
            rs += __shfl_xor(rs, 1);
            rs += __shfl_xor(rs, 2);
            rs += __shfl_xor(rs, 4);
            rs += __shfl_xor(rs, 8);
            Lx[i] = Lx[i] * alpha + rs;
            #pragma unroll
            for (int n = 0; n < 4; ++n) oacc[n][i] *= alpha;
        }
        // P -> LDS (redistribute into A-fragment layout)
        #pragma unroll
        for (int n = 0; n < 4; ++n)
            #pragma unroll
            for (int i = 0; i < 4; ++i)
                Ps[wv][lhi * 4 + i][n * 16 + l15] = f2bf(p[n][i]);
        __syncthreads();

        bf16x8 pf[2];
        pf[0] = *(const bf16x8*)(&Ps[wv][l15][lhi * 8]);
        pf[1] = *(const bf16x8*)(&Ps[wv][l15][32 + lhi * 8]);
        #pragma unroll
        for (int nd = 0; nd < 4; ++nd) {
            #pragma unroll
            for (int kk = 0; kk < 2; ++kk) {
                bf16x8 vf = *(const bf16x8*)(&Vt[nd * 16 + l15][kk * 32 + lhi * 8]);
                oacc[nd] = __builtin_amdgcn_mfma_f32_16x16x32_bf16(pf[kk], vf, oacc[nd], 0, 0, 0);
            }
        }
    }

    // epilogue: O / L -> y (bf16, (B*T, C) layout)
    #pragma unroll
    for (int nd = 0; nd < 4; ++nd) {
        #pragma unroll
        for (int i = 0; i < 4; ++i) {
            int qg  = q0 + wv * 16 + lhi * 4 + i;
            float v = oacc[nd][i] / Lx[i];
            y[(size_t)(b * T_ + qg) * C_ + hoff + nd * 16 + l15] = f2bf(v);
        }
    }
}

// ---------------------------------------------------------------------------
extern "C" void kernel_launch(void* const* d_in, const int* in_sizes, int n_in,
                              void* d_out, int out_size, void* d_ws, size_t ws_size,
                              hipStream_t stream) {
    const float* x      = (const float*)d_in[0];
    const float* W_attn = (const float*)d_in[1];
    const float* b_attn = (const float*)d_in[2];
    const float* W_proj = (const float*)d_in[3];
    const float* b_proj = (const float*)d_in[4];
    float* out = (float*)d_out;

    char* ws = (char*)d_ws;
    unsigned short* xb   = (unsigned short*)(ws);                       // 4096x1024
    unsigned short* wab  = (unsigned short*)(ws + 8388608);             // 3072x1024
    unsigned short* wpb  = (unsigned short*)(ws + 8388608 + 6291456);   // 1024x1024
    unsigned short* qkvb = (unsigned short*)(ws + 16777216);            // 4096x3072
    unsigned short* yb   = (unsigned short*)(ws + 16777216 + 25165824); // 4096x1024

    // fp32 -> bf16 converts
    cvt_bf16<<<(BT_ * C_ / 8 + 255) / 256, 256, 0, stream>>>(x, xb, BT_ * C_ / 8);
    cvt_bf16<<<(C3_ * C_ / 8 + 255) / 256, 256, 0, stream>>>(W_attn, wab, C3_ * C_ / 8);
    cvt_bf16<<<(C_ * C_ / 8 + 255) / 256, 256, 0, stream>>>(W_proj, wpb, C_ * C_ / 8);

    // qkv = x @ W_attn^T + b_attn   (bf16 out)
    gemm_bt<1><<<dim3(C3_ / 128, BT_ / 128), 256, 0, stream>>>(xb, wab, b_attn, qkvb, BT_, C3_, C_);

    // y = causal_attention(q, k, v) (bf16 out)
    attn_fwd<<<dim3(T_ / 64, B_ * H_), 256, 0, stream>>>(qkvb, yb);

    // out = y @ W_proj^T + b_proj   (fp32 out)
    gemm_bt<0><<<dim3(C_ / 128, BT_ / 128), 256, 0, stream>>>(yb, wpb, b_proj, out, BT_, C_, C_);
}

// Round 2
// 258.147 us; speedup vs baseline: 1.2522x; 1.2522x over previous
//
#include <hip/hip_runtime.h>

// ---------------------------------------------------------------------------
// CausalSelfAttention: B=2, T=2048, C=1024, H=16, HD=64
// Inputs fp32, output fp32; internal bf16 MFMA.
// ---------------------------------------------------------------------------

#define B_   2
#define T_   2048
#define C_   1024
#define H_   16
#define HD_  64
#define BT_  (B_ * T_)      // 4096
#define C3_  (3 * C_)       // 3072

typedef __attribute__((ext_vector_type(8))) __bf16 bf16x8;
typedef __attribute__((ext_vector_type(4))) float  f32x4;
typedef __attribute__((ext_vector_type(8))) unsigned short u16x8;

__device__ __forceinline__ unsigned short f2bf(float f) {
    unsigned int u = __float_as_uint(f);
    u = (u + 0x7fffu + ((u >> 16) & 1u)) >> 16;
    return (unsigned short)u;
}

// ---------------- fp32 -> bf16 convert (8 elems/thread) --------------------
__global__ __launch_bounds__(256) void cvt_bf16(const float* __restrict__ in,
                                                unsigned short* __restrict__ out,
                                                int n8) {
    int i = blockIdx.x * 256 + threadIdx.x;
    if (i >= n8) return;
    const float4* p = (const float4*)in;
    float4 f0 = p[i * 2];
    float4 f1 = p[i * 2 + 1];
    u16x8 o;
    o[0] = f2bf(f0.x); o[1] = f2bf(f0.y); o[2] = f2bf(f0.z); o[3] = f2bf(f0.w);
    o[4] = f2bf(f1.x); o[5] = f2bf(f1.y); o[6] = f2bf(f1.z); o[7] = f2bf(f1.w);
    ((u16x8*)out)[i] = o;
}

// ---------------- bf16 GEMM: C[M][N] = A[M][K] * B[N][K]^T + bias ----------
template<int OUT_BF16>
__global__ __launch_bounds__(256) void gemm_bt(const unsigned short* __restrict__ A,
                                               const unsigned short* __restrict__ Bm,
                                               const float* __restrict__ bias,
                                               void* __restrict__ Cv,
                                               int M, int N, int K) {
    __shared__ __align__(16) unsigned short As[128][72];
    __shared__ __align__(16) unsigned short Bs[128][72];

    const int t    = threadIdx.x;
    const int lane = t & 63;
    const int w    = t >> 6;
    const int wr   = w & 1;
    const int wc   = w >> 1;
    const int l15  = lane & 15;
    const int lhi  = lane >> 4;
    const int m0   = blockIdx.y * 128;
    const int n0   = blockIdx.x * 128;

    f32x4 acc[4][4] = {};

    const int nk = K >> 6;
    for (int kb = 0; kb < nk; ++kb) {
        __syncthreads();
        #pragma unroll
        for (int i = 0; i < 4; ++i) {
            int g   = i * 256 + t;
            int row = g >> 3;
            int kc  = g & 7;
            uint4 va = *(const uint4*)(A  + (size_t)(m0 + row) * K + kb * 64 + kc * 8);
            *(uint4*)(&As[row][kc * 8]) = va;
            uint4 vb = *(const uint4*)(Bm + (size_t)(n0 + row) * K + kb * 64 + kc * 8);
            *(uint4*)(&Bs[row][kc * 8]) = vb;
        }
        __syncthreads();
        #pragma unroll
        for (int kk = 0; kk < 2; ++kk) {
            bf16x8 af[4], bfm[4];
            #pragma unroll
            for (int m = 0; m < 4; ++m)
                af[m] = *(const bf16x8*)(&As[wr * 64 + m * 16 + l15][kk * 32 + lhi * 8]);
            #pragma unroll
            for (int n = 0; n < 4; ++n)
                bfm[n] = *(const bf16x8*)(&Bs[wc * 64 + n * 16 + l15][kk * 32 + lhi * 8]);
            #pragma unroll
            for (int m = 0; m < 4; ++m)
                #pragma unroll
                for (int n = 0; n < 4; ++n)
                    acc[m][n] = __builtin_amdgcn_mfma_f32_16x16x32_bf16(af[m], bfm[n], acc[m][n], 0, 0, 0);
        }
    }

    #pragma unroll
    for (int n = 0; n < 4; ++n) {
        int cg = n0 + wc * 64 + n * 16 + l15;
        float bv = bias[cg];
        #pragma unroll
        for (int m = 0; m < 4; ++m) {
            #pragma unroll
            for (int i = 0; i < 4; ++i) {
                int rg  = m0 + wr * 64 + m * 16 + lhi * 4 + i;
                float v = acc[m][n][i] + bv;
                if (OUT_BF16)
                    ((unsigned short*)Cv)[(size_t)rg * N + cg] = f2bf(v);
                else
                    ((float*)Cv)[(size_t)rg * N + cg] = v;
            }
        }
    }
}

// ---------------- causal flash attention -----------------------------------
// grid = (T/64, B*H); block = 256 (4 waves x 16 q-rows). KV tiles of 128.
__global__ __launch_bounds__(256) void attn_fwd(const unsigned short* __restrict__ qkv,
                                                unsigned short* __restrict__ y) {
    __shared__ __align__(16) unsigned short Ks[128][72];
    __shared__ __align__(16) unsigned short Vt[64][136];   // V transposed: [d][key]
    __shared__ __align__(16) unsigned short Ps[4][16][136];

    const int t    = threadIdx.x;
    const int lane = t & 63;
    const int wv   = t >> 6;
    const int l15  = lane & 15;
    const int lhi  = lane >> 4;
    const int b    = blockIdx.y >> 4;
    const int h    = blockIdx.y & 15;
    const int qt   = gridDim.x - 1 - blockIdx.x;  // biggest tiles first
    const int q0   = qt * 64;
    const size_t rowbase = (size_t)b * T_ * C3_;
    const int hoff = h * HD_;

    // Q fragments in registers for the whole kernel
    bf16x8 qf[2];
    {
        int qrow = q0 + wv * 16 + l15;
        const unsigned short* qp = qkv + rowbase + (size_t)qrow * C3_ + hoff + lhi * 8;
        qf[0] = *(const bf16x8*)(qp);
        qf[1] = *(const bf16x8*)(qp + 32);
    }

    float Mx[4], Lx[4];
    f32x4 oacc[4];
    #pragma unroll
    for (int i = 0; i < 4; ++i) { Mx[i] = -1e30f; Lx[i] = 0.f; }
    #pragma unroll
    for (int n = 0; n < 4; ++n) oacc[n] = f32x4{0.f, 0.f, 0.f, 0.f};

    // V staging: thread -> (d, key-chunk); column-reads are 128B-contiguous per inst
    const int vd = t & 63;
    const int vk = t >> 6;
    const unsigned short* vcol = qkv + rowbase + 2 * C_ + hoff + vd;
    const unsigned short* krow = qkv + rowbase + C_ + hoff;

    const int niter = (qt + 2) >> 1;
    for (int it = 0; it < niter; ++it) {
        const int k0 = it * 128;
        __syncthreads();
        // K tile: coalesced b128
        #pragma unroll
        for (int i = 0; i < 4; ++i) {
            int g   = i * 256 + t;
            int row = g >> 3;
            int kc  = g & 7;
            *(uint4*)(&Ks[row][kc * 8]) =
                *(const uint4*)(krow + (size_t)(k0 + row) * C3_ + kc * 8);
        }
        // V tile transposed via transposed global reads + b128 LDS writes
        #pragma unroll
        for (int pp = 0; pp < 4; ++pp) {
            int kb = pp * 32 + vk * 8;
            u16x8 vv;
            #pragma unroll
            for (int j = 0; j < 8; ++j)
                vv[j] = vcol[(size_t)(k0 + kb + j) * C3_];
            *(u16x8*)(&Vt[vd][kb]) = vv;
        }
        __syncthreads();

        // S = Q K^T  (16 q-rows x 128 keys per wave)
        f32x4 sacc[8];
        #pragma unroll
        for (int n = 0; n < 8; ++n) sacc[n] = f32x4{0.f, 0.f, 0.f, 0.f};
        __builtin_amdgcn_s_setprio(1);
        #pragma unroll
        for (int kk = 0; kk < 2; ++kk) {
            #pragma unroll
            for (int n = 0; n < 8; ++n) {
                bf16x8 kf = *(const bf16x8*)(&Ks[n * 16 + l15][kk * 32 + lhi * 8]);
                sacc[n] = __builtin_amdgcn_mfma_f32_16x16x32_bf16(qf[kk], kf, sacc[n], 0, 0, 0);
            }
        }
        __builtin_amdgcn_s_setprio(0);

        // scale + causal mask (skip mask on full tiles — uniform branch)
        float p[8][4];
        if (k0 + 127 <= q0) {
            #pragma unroll
            for (int n = 0; n < 8; ++n)
                #pragma unroll
                for (int i = 0; i < 4; ++i)
                    p[n][i] = sacc[n][i] * 0.125f;
        } else {
            const int qgb = q0 + wv * 16 + lhi * 4;
            #pragma unroll
            for (int n = 0; n < 8; ++n) {
                int kg = k0 + n * 16 + l15;
                #pragma unroll
                for (int i = 0; i < 4; ++i)
                    p[n][i] = (kg <= qgb + i) ? sacc[n][i] * 0.125f : -1e30f;
            }
        }

        // online softmax (row reductions across 16 lanes)
        #pragma unroll
        for (int i = 0; i < 4; ++i) {
            float vm = p[0][i];
            #pragma unroll
            for (int n = 1; n < 8; ++n) vm = fmaxf(vm, p[n][i]);
            vm = fmaxf(vm, __shfl_xor(vm, 1));
            vm = fmaxf(vm, __shfl_xor(vm, 2));
            vm = fmaxf(vm, __shfl_xor(vm, 4));
            vm = fmaxf(vm, __shfl_xor(vm, 8));
            float Mn = fmaxf(Mx[i], vm);
            float al = __expf(Mx[i] - Mn);
            Mx[i] = Mn;
            float rs = 0.f;
            #pragma unroll
            for (int n = 0; n < 8; ++n) {
                float e = __expf(p[n][i] - Mn);
                p[n][i] = e;
                rs += e;
            }
            rs += __shfl_xor(rs, 1);
            rs += __shfl_xor(rs, 2);
            rs += __shfl_xor(rs, 4);
            rs += __shfl_xor(rs, 8);
            Lx[i] = Lx[i] * al + rs;
            #pragma unroll
            for (int n = 0; n < 4; ++n) oacc[n][i] *= al;
        }

        // P -> LDS (wave-private: no barrier, just drain LDS writes)
        #pragma unroll
        for (int n = 0; n < 8; ++n)
            #pragma unroll
            for (int i = 0; i < 4; ++i)
                Ps[wv][lhi * 4 + i][n * 16 + l15] = f2bf(p[n][i]);
        asm volatile("s_waitcnt lgkmcnt(0)" ::: "memory");

        __builtin_amdgcn_s_setprio(1);
        #pragma unroll
        for (int kk = 0; kk < 4; ++kk) {
            bf16x8 pf = *(const bf16x8*)(&Ps[wv][l15][kk * 32 + lhi * 8]);
            #pragma unroll
            for (int nd = 0; nd < 4; ++nd) {
                bf16x8 vf = *(const bf16x8*)(&Vt[nd * 16 + l15][kk * 32 + lhi * 8]);
                oacc[nd] = __builtin_amdgcn_mfma_f32_16x16x32_bf16(pf, vf, oacc[nd], 0, 0, 0);
            }
        }
        __builtin_amdgcn_s_setprio(0);
    }

    // epilogue: O / L -> y (bf16, (B*T, C) layout)
    #pragma unroll
    for (int nd = 0; nd < 4; ++nd) {
        #pragma unroll
        for (int i = 0; i < 4; ++i) {
            int qg  = q0 + wv * 16 + lhi * 4 + i;
            float v = oacc[nd][i] / Lx[i];
            y[(size_t)(b * T_ + qg) * C_ + hoff + nd * 16 + l15] = f2bf(v);
        }
    }
}

// ---------------------------------------------------------------------------
extern "C" void kernel_launch(void* const* d_in, const int* in_sizes, int n_in,
                              void* d_out, int out_size, void* d_ws, size_t ws_size,
                              hipStream_t stream) {
    const float* x      = (const float*)d_in[0];
    const float* W_attn = (const float*)d_in[1];
    const float* b_attn = (const float*)d_in[2];
    const float* W_proj = (const float*)d_in[3];
    const float* b_proj = (const float*)d_in[4];
    float* out = (float*)d_out;

    char* ws = (char*)d_ws;
    unsigned short* xb   = (unsigned short*)(ws);                       // 4096x1024
    unsigned short* wab  = (unsigned short*)(ws + 8388608);             // 3072x1024
    unsigned short* wpb  = (unsigned short*)(ws + 8388608 + 6291456);   // 1024x1024
    unsigned short* qkvb = (unsigned short*)(ws + 16777216);            // 4096x3072
    unsigned short* yb   = (unsigned short*)(ws + 16777216 + 25165824); // 4096x1024

    cvt_bf16<<<(BT_ * C_ / 8 + 255) / 256, 256, 0, stream>>>(x, xb, BT_ * C_ / 8);
    cvt_bf16<<<(C3_ * C_ / 8 + 255) / 256, 256, 0, stream>>>(W_attn, wab, C3_ * C_ / 8);
    cvt_bf16<<<(C_ * C_ / 8 + 255) / 256, 256, 0, stream>>>(W_proj, wpb, C_ * C_ / 8);

    gemm_bt<1><<<dim3(C3_ / 128, BT_ / 128), 256, 0, stream>>>(xb, wab, b_attn, qkvb, BT_, C3_, C_);

    attn_fwd<<<dim3(T_ / 64, B_ * H_), 256, 0, stream>>>(qkvb, yb);

    gemm_bt<0><<<dim3(C_ / 128, BT_ / 128), 256, 0, stream>>>(yb, wpb, b_proj, out, BT_, C_, C_);
}